// Round 1
// baseline (149.312 us; speedup 1.0000x reference)
//
#include <hip/hip_runtime.h>
#include <cmath>

#define B_    64
#define G_    8
#define DIM_  32
#define E_    8
#define OC_   10
#define LL    4096
#define LP    4094
#define COMBINE_SIZE (B_ * G_ * OC_ * LP)   // 20,961,280

// ---------------- gating: logits -> softmax -> top2 -> gates --------------
// grid: 64 blocks (one per b), 64 threads (g = tid>>3, e = tid&7)
__global__ void gate_kernel(const float* __restrict__ x,
                            const float* __restrict__ wg,
                            float* __restrict__ gws,    // [B,G,E] gates
                            float* __restrict__ gout) { // [B,E,G] output
    const int b   = blockIdx.x;
    const int tid = threadIdx.x;
    __shared__ float gin[G_ * 160];
    for (int i = tid; i < G_ * 160; i += 64) {
        int g = i / 160, r = i - g * 160;
        int d = r / 5,   t = r - d * 5;
        gin[i] = x[((size_t)b * (G_ * DIM_) + g * DIM_ + d) * LL + (LL - 6 + t)];
    }
    __syncthreads();
    const int g = tid >> 3, e = tid & 7;
    const float* gp = gin + g * 160;
    const float* wp = wg + (size_t)g * 160 * E_ + e;
    float acc = 0.f;
    for (int i = 0; i < 160; ++i) acc = fmaf(gp[i], wp[i * E_], acc);

    // softmax across the 8 lanes of this octet
    float m = acc;
    #pragma unroll
    for (int s = 4; s >= 1; s >>= 1) m = fmaxf(m, __shfl_xor(m, s));
    float p = expf(acc - m);
    float sum = p;
    #pragma unroll
    for (int s = 4; s >= 1; s >>= 1) sum += __shfl_xor(sum, s);
    p /= sum;

    // every lane gathers all 8 probs, does identical top-2
    float pv[8];
    const int base = tid & ~7;
    #pragma unroll
    for (int j = 0; j < 8; ++j) pv[j] = __shfl(p, base + j);
    int i1 = 0; float v1 = pv[0];
    #pragma unroll
    for (int j = 1; j < 8; ++j) if (pv[j] > v1) { v1 = pv[j]; i1 = j; }
    int i2 = -1; float v2 = -1.f;
    #pragma unroll
    for (int j = 0; j < 8; ++j) if (j != i1 && pv[j] > v2) { v2 = pv[j]; i2 = j; }
    const float denom = v1 + v2 + 1e-6f;
    const float gate = (e == i1) ? v1 / denom : ((e == i2) ? v2 / denom : 0.f);
    gws[(b * G_ + g) * E_ + e]   = gate;
    gout[b * (E_ * G_) + e * G_ + g] = gate;
}

// ---------------- load-balancing loss (1 block, 64 threads) ---------------
__global__ void loss_kernel(const float* __restrict__ gws,
                            float* __restrict__ loss_out) {
    const int tid = threadIdx.x;   // tid = g*8 + e
    float imp = 0.f, ld = 0.f;
    for (int b = 0; b < B_; ++b) {
        const float v = gws[b * 64 + tid];
        imp += v;
        ld  += (v > 0.f) ? 1.f : 0.f;
    }
    // per-octet (per-g) mean/var over the 8 experts, ddof=1
    float si = imp, sl = ld;
    #pragma unroll
    for (int msk = 1; msk <= 4; msk <<= 1) { si += __shfl_xor(si, msk); sl += __shfl_xor(sl, msk); }
    const float mi = si * 0.125f, ml = sl * 0.125f;
    float di = imp - mi, dl = ld - ml;
    float vi = di * di, vl = dl * dl;
    #pragma unroll
    for (int msk = 1; msk <= 4; msk <<= 1) { vi += __shfl_xor(vi, msk); vl += __shfl_xor(vl, msk); }
    const float cvi = (vi / 7.f) / (mi * mi + 1e-10f);
    const float cvl = (vl / 7.f) / (ml * ml + 1e-10f);
    float c = ((tid & 7) == 0) ? (cvi + cvl) : 0.f;
    #pragma unroll
    for (int msk = 1; msk < 64; msk <<= 1) c += __shfl_xor(c, msk);
    if (tid == 0) *loss_out = 0.01f * c;
}

// ---------------- main fused conv1 -> tanh -> gated conv2 ------------------
// grid: 2048 blocks = 64(b) * 8(g) * 4(tile); 256 threads; 4 l per thread
__global__ __launch_bounds__(256) void conv_kernel(
        const float* __restrict__ x,
        const float* __restrict__ w1, const float* __restrict__ b1,
        const float* __restrict__ w2, const float* __restrict__ b2,
        const float* __restrict__ gws,
        float* __restrict__ out) {
    const int tid  = threadIdx.x;
    const int tile = blockIdx.x & 3;
    const int bg   = blockIdx.x >> 2;
    const int g    = bg & 7;
    const int b    = bg >> 3;

    __shared__ float w1s[OC_ * 96];     // [o][d][t] -> o*96 + d*3 + t
    __shared__ float b1s[OC_];
    __shared__ float weff[OC_ * OC_];   // [dd][j]
    __shared__ float beff[OC_];

    for (int i = tid; i < OC_ * 96; i += 256) w1s[i] = w1[g * 960 + i];
    if (tid < OC_) b1s[tid] = b1[g * OC_ + tid];
    const float* gp = gws + bg * E_;
    if (tid < 100) {
        const int dd = tid / 10, j = tid - dd * 10;
        float s = 0.f;
        #pragma unroll
        for (int e = 0; e < 8; ++e)
            s = fmaf(gp[e], w2[(g * 80 + dd * 8 + e) * 10 + j], s);
        weff[tid] = s;
    } else if (tid < 110) {
        const int dd = tid - 100;
        float s = 0.f;
        #pragma unroll
        for (int e = 0; e < 8; ++e)
            s = fmaf(gp[e], b2[g * 80 + dd * 8 + e], s);
        beff[dd] = s;
    }
    __syncthreads();

    const int l = tile * 1024 + tid * 4;
    const float* xb = x + ((size_t)b * 256 + g * 32) * LL + l;

    float acc[10][4];
    #pragma unroll
    for (int o = 0; o < 10; ++o) {
        const float bv = b1s[o];
        acc[o][0] = bv; acc[o][1] = bv; acc[o][2] = bv; acc[o][3] = bv;
    }

    auto body = [&](int d, float x0, float x1, float x2,
                    float x3, float x4, float x5) {
        const float* wrow = w1s + d * 3;
        #pragma unroll
        for (int o = 0; o < 10; ++o) {
            const float w0 = wrow[o * 96];
            const float wA = wrow[o * 96 + 1];
            const float wB = wrow[o * 96 + 2];
            acc[o][0] = fmaf(x2, wB, fmaf(x1, wA, fmaf(x0, w0, acc[o][0])));
            acc[o][1] = fmaf(x3, wB, fmaf(x2, wA, fmaf(x1, w0, acc[o][1])));
            acc[o][2] = fmaf(x4, wB, fmaf(x3, wA, fmaf(x2, w0, acc[o][2])));
            acc[o][3] = fmaf(x5, wB, fmaf(x4, wA, fmaf(x3, w0, acc[o][3])));
        }
    };

    if (tile < 3) {                      // interior: fully in-bounds
        #pragma unroll 4
        for (int d = 0; d < 32; ++d) {
            const float4 xm = *reinterpret_cast<const float4*>(xb + (size_t)d * LL);
            const float2 xh = *reinterpret_cast<const float2*>(xb + (size_t)d * LL + 4);
            body(d, xm.x, xm.y, xm.z, xm.w, xh.x, xh.y);
        }
    } else {                             // tail tile: guarded scalar loads
        #pragma unroll 2
        for (int d = 0; d < 32; ++d) {
            const float* xr = xb + (size_t)d * LL;
            float xv[6];
            #pragma unroll
            for (int k = 0; k < 6; ++k)
                xv[k] = (l + k < LL) ? xr[k] : 0.f;
            body(d, xv[0], xv[1], xv[2], xv[3], xv[4], xv[5]);
        }
    }

    #pragma unroll
    for (int o = 0; o < 10; ++o) {
        acc[o][0] = tanhf(acc[o][0]);
        acc[o][1] = tanhf(acc[o][1]);
        acc[o][2] = tanhf(acc[o][2]);
        acc[o][3] = tanhf(acc[o][3]);
    }

    float* ob = out + (size_t)bg * OC_ * LP + l;
    if (tile < 3) {
        #pragma unroll
        for (int dd = 0; dd < 10; ++dd) {
            const float* wr = weff + dd * 10;
            float r0 = beff[dd], r1 = r0, r2 = r0, r3 = r0;
            #pragma unroll
            for (int j = 0; j < 10; ++j) {
                const float w = wr[j];
                r0 = fmaf(acc[j][0], w, r0);
                r1 = fmaf(acc[j][1], w, r1);
                r2 = fmaf(acc[j][2], w, r2);
                r3 = fmaf(acc[j][3], w, r3);
            }
            float* op = ob + (size_t)dd * LP;
            *reinterpret_cast<float2*>(op)     = make_float2(r0, r1);
            *reinterpret_cast<float2*>(op + 2) = make_float2(r2, r3);
        }
    } else {
        #pragma unroll
        for (int dd = 0; dd < 10; ++dd) {
            const float* wr = weff + dd * 10;
            float r[4] = {beff[dd], beff[dd], beff[dd], beff[dd]};
            #pragma unroll
            for (int j = 0; j < 10; ++j) {
                const float w = wr[j];
                r[0] = fmaf(acc[j][0], w, r[0]);
                r[1] = fmaf(acc[j][1], w, r[1]);
                r[2] = fmaf(acc[j][2], w, r[2]);
                r[3] = fmaf(acc[j][3], w, r[3]);
            }
            float* op = ob + (size_t)dd * LP;
            #pragma unroll
            for (int v = 0; v < 4; ++v)
                if (l + v < LP) op[v] = r[v];
        }
    }
}

extern "C" void kernel_launch(void* const* d_in, const int* in_sizes, int n_in,
                              void* d_out, int out_size, void* d_ws, size_t ws_size,
                              hipStream_t stream) {
    (void)in_sizes; (void)n_in; (void)out_size; (void)ws_size;
    const float* x  = (const float*)d_in[0];
    const float* w1 = (const float*)d_in[1];
    const float* b1 = (const float*)d_in[2];
    const float* w2 = (const float*)d_in[3];
    const float* b2 = (const float*)d_in[4];
    const float* wg = (const float*)d_in[5];
    float* out      = (float*)d_out;
    float* gws      = (float*)d_ws;                 // [B,G,E] gates scratch
    float* loss_out = out + COMBINE_SIZE;
    float* gout     = out + COMBINE_SIZE + 1;

    gate_kernel<<<B_, 64, 0, stream>>>(x, wg, gws, gout);
    loss_kernel<<<1, 64, 0, stream>>>(gws, loss_out);
    conv_kernel<<<B_ * G_ * 4, 256, 0, stream>>>(x, w1, b1, w2, b2, gws, out);
}

// Round 2
// 145.836 us; speedup vs baseline: 1.0238x; 1.0238x over previous
//
#include <hip/hip_runtime.h>
#include <cmath>

#define B_    64
#define G_    8
#define DIM_  32
#define E_    8
#define OC_   10
#define LL    4096
#define LP    4094
#define COMBINE_SIZE (B_ * G_ * OC_ * LP)   // 20,961,280

// fast tanh: 1 - 2/(e^{2v}+1), clamped; ~5 VALU instrs
__device__ __forceinline__ float fast_tanh(float v) {
    v = fminf(fmaxf(v, -12.f), 12.f);
    const float e = __expf(2.f * v);
    return 1.f - 2.f * __builtin_amdgcn_rcpf(e + 1.f);
}

// ---- repack conv1 weights: w1[g][o][d][t] -> w1t[g][d][o*3+t] (row pad 32)
__global__ void repack_kernel(const float* __restrict__ w1,
                              float* __restrict__ w1t) {
    const int i = blockIdx.x * 256 + threadIdx.x;   // over 8*32*30
    if (i >= G_ * 32 * 30) return;
    const int g = i / 960, r = i - g * 960;
    const int d = r / 30,  s = r - d * 30;
    const int o = s / 3,   t = s - o * 3;
    w1t[g * 1024 + d * 32 + s] = w1[g * 960 + o * 96 + d * 3 + t];
}

// ---------------- gating: logits -> softmax -> top2 -> gates --------------
__global__ void gate_kernel(const float* __restrict__ x,
                            const float* __restrict__ wg,
                            float* __restrict__ gws,    // [B,G,E] gates
                            float* __restrict__ gout) { // [B,E,G] output
    const int b   = blockIdx.x;
    const int tid = threadIdx.x;
    __shared__ float gin[G_ * 160];
    for (int i = tid; i < G_ * 160; i += 64) {
        int g = i / 160, r = i - g * 160;
        int d = r / 5,   t = r - d * 5;
        gin[i] = x[((size_t)b * (G_ * DIM_) + g * DIM_ + d) * LL + (LL - 6 + t)];
    }
    __syncthreads();
    const int g = tid >> 3, e = tid & 7;
    const float* gp = gin + g * 160;
    const float* wp = wg + (size_t)g * 160 * E_ + e;
    float acc = 0.f;
    for (int i = 0; i < 160; ++i) acc = fmaf(gp[i], wp[i * E_], acc);

    float m = acc;
    #pragma unroll
    for (int s = 4; s >= 1; s >>= 1) m = fmaxf(m, __shfl_xor(m, s));
    float p = expf(acc - m);
    float sum = p;
    #pragma unroll
    for (int s = 4; s >= 1; s >>= 1) sum += __shfl_xor(sum, s);
    p /= sum;

    float pv[8];
    const int base = tid & ~7;
    #pragma unroll
    for (int j = 0; j < 8; ++j) pv[j] = __shfl(p, base + j);
    int i1 = 0; float v1 = pv[0];
    #pragma unroll
    for (int j = 1; j < 8; ++j) if (pv[j] > v1) { v1 = pv[j]; i1 = j; }
    int i2 = -1; float v2 = -1.f;
    #pragma unroll
    for (int j = 0; j < 8; ++j) if (j != i1 && pv[j] > v2) { v2 = pv[j]; i2 = j; }
    const float denom = v1 + v2 + 1e-6f;
    const float gate = (e == i1) ? v1 / denom : ((e == i2) ? v2 / denom : 0.f);
    gws[(b * G_ + g) * E_ + e]   = gate;
    gout[b * (E_ * G_) + e * G_ + g] = gate;
}

// ---------------- load-balancing loss (1 block, 64 threads) ---------------
__global__ void loss_kernel(const float* __restrict__ gws,
                            float* __restrict__ loss_out) {
    const int tid = threadIdx.x;   // tid = g*8 + e
    float imp = 0.f, ld = 0.f;
    for (int b = 0; b < B_; ++b) {
        const float v = gws[b * 64 + tid];
        imp += v;
        ld  += (v > 0.f) ? 1.f : 0.f;
    }
    float si = imp, sl = ld;
    #pragma unroll
    for (int msk = 1; msk <= 4; msk <<= 1) { si += __shfl_xor(si, msk); sl += __shfl_xor(sl, msk); }
    const float mi = si * 0.125f, ml = sl * 0.125f;
    float di = imp - mi, dl = ld - ml;
    float vi = di * di, vl = dl * dl;
    #pragma unroll
    for (int msk = 1; msk <= 4; msk <<= 1) { vi += __shfl_xor(vi, msk); vl += __shfl_xor(vl, msk); }
    const float cvi = (vi / 7.f) / (mi * mi + 1e-10f);
    const float cvl = (vl / 7.f) / (ml * ml + 1e-10f);
    float c = ((tid & 7) == 0) ? (cvi + cvl) : 0.f;
    #pragma unroll
    for (int msk = 1; msk < 64; msk <<= 1) c += __shfl_xor(c, msk);
    if (tid == 0) *loss_out = 0.01f * c;
}

// ---------------- main fused conv1 -> tanh -> gated conv2 ------------------
// grid: 2048 blocks = 64(b) * 8(g) * 4(tile); 256 threads; 4 l per thread
// conv1 weights read wave-uniform from global (scalarized -> s_load / K$),
// so the only LDS in the hot loop is none; weff/beff read once in epilogue.
__global__ __launch_bounds__(256) void conv_kernel(
        const float* __restrict__ x,
        const float* __restrict__ w1t,   // repacked [g][d][32]
        const float* __restrict__ b1,
        const float* __restrict__ w2, const float* __restrict__ b2,
        const float* __restrict__ gws,
        float* __restrict__ out) {
    const int tid  = threadIdx.x;
    const int tile = blockIdx.x & 3;
    const int bg   = blockIdx.x >> 2;
    const int g    = bg & 7;
    const int b    = bg >> 3;

    __shared__ float weff[OC_ * OC_];   // [dd][j]
    __shared__ float beff[OC_];

    const float* gp = gws + bg * E_;
    if (tid < 100) {
        const int dd = tid / 10, j = tid - dd * 10;
        float s = 0.f;
        #pragma unroll
        for (int e = 0; e < 8; ++e)
            s = fmaf(gp[e], w2[(g * 80 + dd * 8 + e) * 10 + j], s);
        weff[tid] = s;
    } else if (tid < 110) {
        const int dd = tid - 100;
        float s = 0.f;
        #pragma unroll
        for (int e = 0; e < 8; ++e)
            s = fmaf(gp[e], b2[g * 80 + dd * 8 + e], s);
        beff[dd] = s;
    }
    __syncthreads();

    const int l = tile * 1024 + tid * 4;
    const float* xb = x + ((size_t)b * 256 + g * 32) * LL + l;
    const float* wgt = w1t + g * 1024;          // wave-uniform base
    const float* b1g = b1 + g * OC_;            // wave-uniform

    float acc[10][4];
    #pragma unroll
    for (int o = 0; o < 10; ++o) {
        const float bv = b1g[o];
        acc[o][0] = bv; acc[o][1] = bv; acc[o][2] = bv; acc[o][3] = bv;
    }

    auto body = [&](const float* wr, float x0, float x1, float x2,
                    float x3, float x4, float x5) {
        #pragma unroll
        for (int o = 0; o < 10; ++o) {
            const float w0 = wr[o * 3];
            const float wA = wr[o * 3 + 1];
            const float wB = wr[o * 3 + 2];
            acc[o][0] = fmaf(x2, wB, fmaf(x1, wA, fmaf(x0, w0, acc[o][0])));
            acc[o][1] = fmaf(x3, wB, fmaf(x2, wA, fmaf(x1, w0, acc[o][1])));
            acc[o][2] = fmaf(x4, wB, fmaf(x3, wA, fmaf(x2, w0, acc[o][2])));
            acc[o][3] = fmaf(x5, wB, fmaf(x4, wA, fmaf(x3, w0, acc[o][3])));
        }
    };

    if (tile < 3) {                      // interior: fully in-bounds
        #pragma unroll 4
        for (int d = 0; d < 32; ++d) {
            const float4 xm = *reinterpret_cast<const float4*>(xb + (size_t)d * LL);
            const float2 xh = *reinterpret_cast<const float2*>(xb + (size_t)d * LL + 4);
            body(wgt + d * 32, xm.x, xm.y, xm.z, xm.w, xh.x, xh.y);
        }
    } else {                             // tail tile: guarded scalar loads
        #pragma unroll 2
        for (int d = 0; d < 32; ++d) {
            const float* xr = xb + (size_t)d * LL;
            float xv[6];
            #pragma unroll
            for (int k = 0; k < 6; ++k)
                xv[k] = (l + k < LL) ? xr[k] : 0.f;
            body(wgt + d * 32, xv[0], xv[1], xv[2], xv[3], xv[4], xv[5]);
        }
    }

    #pragma unroll
    for (int o = 0; o < 10; ++o) {
        acc[o][0] = fast_tanh(acc[o][0]);
        acc[o][1] = fast_tanh(acc[o][1]);
        acc[o][2] = fast_tanh(acc[o][2]);
        acc[o][3] = fast_tanh(acc[o][3]);
    }

    float* ob = out + (size_t)bg * OC_ * LP + l;
    if (tile < 3) {
        #pragma unroll
        for (int dd = 0; dd < 10; ++dd) {
            const float* wr = weff + dd * 10;
            float r0 = beff[dd], r1 = r0, r2 = r0, r3 = r0;
            #pragma unroll
            for (int j = 0; j < 10; ++j) {
                const float w = wr[j];
                r0 = fmaf(acc[j][0], w, r0);
                r1 = fmaf(acc[j][1], w, r1);
                r2 = fmaf(acc[j][2], w, r2);
                r3 = fmaf(acc[j][3], w, r3);
            }
            float* op = ob + (size_t)dd * LP;
            *reinterpret_cast<float2*>(op)     = make_float2(r0, r1);
            *reinterpret_cast<float2*>(op + 2) = make_float2(r2, r3);
        }
    } else {
        #pragma unroll
        for (int dd = 0; dd < 10; ++dd) {
            const float* wr = weff + dd * 10;
            float r[4] = {beff[dd], beff[dd], beff[dd], beff[dd]};
            #pragma unroll
            for (int j = 0; j < 10; ++j) {
                const float w = wr[j];
                r[0] = fmaf(acc[j][0], w, r[0]);
                r[1] = fmaf(acc[j][1], w, r[1]);
                r[2] = fmaf(acc[j][2], w, r[2]);
                r[3] = fmaf(acc[j][3], w, r[3]);
            }
            float* op = ob + (size_t)dd * LP;
            #pragma unroll
            for (int v = 0; v < 4; ++v)
                if (l + v < LP) op[v] = r[v];
        }
    }
}

extern "C" void kernel_launch(void* const* d_in, const int* in_sizes, int n_in,
                              void* d_out, int out_size, void* d_ws, size_t ws_size,
                              hipStream_t stream) {
    (void)in_sizes; (void)n_in; (void)out_size; (void)ws_size;
    const float* x  = (const float*)d_in[0];
    const float* w1 = (const float*)d_in[1];
    const float* b1 = (const float*)d_in[2];
    const float* w2 = (const float*)d_in[3];
    const float* b2 = (const float*)d_in[4];
    const float* wg = (const float*)d_in[5];
    float* out      = (float*)d_out;
    float* gws      = (float*)d_ws;                         // 16 KB: [B,G,E]
    float* w1t      = (float*)d_ws + B_ * G_ * E_;          // 32 KB: [g][d][32]
    float* loss_out = out + COMBINE_SIZE;
    float* gout     = out + COMBINE_SIZE + 1;

    repack_kernel<<<(G_ * 32 * 30 + 255) / 256, 256, 0, stream>>>(w1, w1t);
    gate_kernel<<<B_, 64, 0, stream>>>(x, wg, gws, gout);
    loss_kernel<<<1, 64, 0, stream>>>(gws, loss_out);
    conv_kernel<<<B_ * G_ * 4, 256, 0, stream>>>(x, w1t, b1, w2, b2, gws, out);
}

// Round 3
// 112.562 us; speedup vs baseline: 1.3265x; 1.2956x over previous
//
#include <hip/hip_runtime.h>
#include <cmath>

#define B_    64
#define G_    8
#define DIM_  32
#define E_    8
#define OC_   10
#define LL    4096
#define LP    4094
#define COMBINE_SIZE (B_ * G_ * OC_ * LP)   // 20,961,280

// fast tanh: 1 - 2/(e^{2v}+1), clamped; ~5 VALU instrs
__device__ __forceinline__ float fast_tanh(float v) {
    v = fminf(fmaxf(v, -12.f), 12.f);
    const float e = __expf(2.f * v);
    return 1.f - 2.f * __builtin_amdgcn_rcpf(e + 1.f);
}

// ---- repack conv1 weights: w1[g][o][d][t] -> w1t[g][d][o*3+t] (row pad 32)
__global__ void repack_kernel(const float* __restrict__ w1,
                              float* __restrict__ w1t) {
    const int i = blockIdx.x * 256 + threadIdx.x;   // over 8*32*30
    if (i >= G_ * 32 * 30) return;
    const int g = i / 960, r = i - g * 960;
    const int d = r / 30,  s = r - d * 30;
    const int o = s / 3,   t = s - o * 3;
    w1t[g * 1024 + d * 32 + s] = w1[g * 960 + o * 96 + d * 3 + t];
}

// ---------------- gating: logits -> softmax -> top2 -> gates --------------
__global__ void gate_kernel(const float* __restrict__ x,
                            const float* __restrict__ wg,
                            float* __restrict__ gws,    // [B,G,E] gates
                            float* __restrict__ gout) { // [B,E,G] output
    const int b   = blockIdx.x;
    const int tid = threadIdx.x;
    __shared__ float gin[G_ * 160];
    for (int i = tid; i < G_ * 160; i += 64) {
        int g = i / 160, r = i - g * 160;
        int d = r / 5,   t = r - d * 5;
        gin[i] = x[((size_t)b * (G_ * DIM_) + g * DIM_ + d) * LL + (LL - 6 + t)];
    }
    __syncthreads();
    const int g = tid >> 3, e = tid & 7;
    const float* gp = gin + g * 160;
    const float* wp = wg + (size_t)g * 160 * E_ + e;
    float acc = 0.f;
    for (int i = 0; i < 160; ++i) acc = fmaf(gp[i], wp[i * E_], acc);

    float m = acc;
    #pragma unroll
    for (int s = 4; s >= 1; s >>= 1) m = fmaxf(m, __shfl_xor(m, s));
    float p = expf(acc - m);
    float sum = p;
    #pragma unroll
    for (int s = 4; s >= 1; s >>= 1) sum += __shfl_xor(sum, s);
    p /= sum;

    float pv[8];
    const int base = tid & ~7;
    #pragma unroll
    for (int j = 0; j < 8; ++j) pv[j] = __shfl(p, base + j);
    int i1 = 0; float v1 = pv[0];
    #pragma unroll
    for (int j = 1; j < 8; ++j) if (pv[j] > v1) { v1 = pv[j]; i1 = j; }
    int i2 = -1; float v2 = -1.f;
    #pragma unroll
    for (int j = 0; j < 8; ++j) if (j != i1 && pv[j] > v2) { v2 = pv[j]; i2 = j; }
    const float denom = v1 + v2 + 1e-6f;
    const float gate = (e == i1) ? v1 / denom : ((e == i2) ? v2 / denom : 0.f);
    gws[(b * G_ + g) * E_ + e]   = gate;
    gout[b * (E_ * G_) + e * G_ + g] = gate;
}

// ---------------- load-balancing loss (1 block, 64 threads) ---------------
__global__ void loss_kernel(const float* __restrict__ gws,
                            float* __restrict__ loss_out) {
    const int tid = threadIdx.x;   // tid = g*8 + e
    float imp = 0.f, ld = 0.f;
    for (int b = 0; b < B_; ++b) {
        const float v = gws[b * 64 + tid];
        imp += v;
        ld  += (v > 0.f) ? 1.f : 0.f;
    }
    float si = imp, sl = ld;
    #pragma unroll
    for (int msk = 1; msk <= 4; msk <<= 1) { si += __shfl_xor(si, msk); sl += __shfl_xor(sl, msk); }
    const float mi = si * 0.125f, ml = sl * 0.125f;
    float di = imp - mi, dl = ld - ml;
    float vi = di * di, vl = dl * dl;
    #pragma unroll
    for (int msk = 1; msk <= 4; msk <<= 1) { vi += __shfl_xor(vi, msk); vl += __shfl_xor(vl, msk); }
    const float cvi = (vi / 7.f) / (mi * mi + 1e-10f);
    const float cvl = (vl / 7.f) / (ml * ml + 1e-10f);
    float c = ((tid & 7) == 0) ? (cvi + cvl) : 0.f;
    #pragma unroll
    for (int msk = 1; msk < 64; msk <<= 1) c += __shfl_xor(c, msk);
    if (tid == 0) *loss_out = 0.01f * c;
}

// ---------------- main fused conv1 -> tanh -> gated conv2 ------------------
// grid: 1024 blocks = 64(b)*8(g)*2(tile); 256 threads; 8 l per thread.
// Explicit A/B register double-buffer over d so loads for d+1 are in flight
// while computing d. Weights are wave-uniform global reads (s_load / K$).
__global__ __launch_bounds__(256) void conv_kernel(
        const float* __restrict__ x,
        const float* __restrict__ w1t,   // repacked [g][d][32]
        const float* __restrict__ b1,
        const float* __restrict__ w2, const float* __restrict__ b2,
        const float* __restrict__ gws,
        float* __restrict__ out) {
    const int tid  = threadIdx.x;
    const int tile = blockIdx.x & 1;
    const int bg   = blockIdx.x >> 1;
    const int g    = bg & 7;
    const int b    = bg >> 3;

    __shared__ float weff[OC_ * OC_];   // [dd][j]
    __shared__ float beff[OC_];

    const float* gp = gws + bg * E_;
    if (tid < 100) {
        const int dd = tid / 10, j = tid - dd * 10;
        float s = 0.f;
        #pragma unroll
        for (int e = 0; e < 8; ++e)
            s = fmaf(gp[e], w2[(g * 80 + dd * 8 + e) * 10 + j], s);
        weff[tid] = s;
    } else if (tid < 110) {
        const int dd = tid - 100;
        float s = 0.f;
        #pragma unroll
        for (int e = 0; e < 8; ++e)
            s = fmaf(gp[e], b2[g * 80 + dd * 8 + e], s);
        beff[dd] = s;
    }
    __syncthreads();

    const int l = tile * 2048 + tid * 8;
    const float* xb  = x + ((size_t)b * 256 + g * 32) * LL + l;
    const float* wgt = w1t + g * 1024;          // wave-uniform base
    const float* b1g = b1 + g * OC_;            // wave-uniform
    const bool hvalid = (l + 9 < LL);           // only false for tid=255,tile=1

    float acc[10][8];
    #pragma unroll
    for (int o = 0; o < 10; ++o) {
        const float bv = b1g[o];
        #pragma unroll
        for (int k = 0; k < 8; ++k) acc[o][k] = bv;
    }

#define XLOAD(P0, P1, PH, dd)                                                   \
    P0 = *reinterpret_cast<const float4*>(xb + (size_t)(dd) * LL);              \
    P1 = *reinterpret_cast<const float4*>(xb + (size_t)(dd) * LL + 4);          \
    PH = hvalid ? *reinterpret_cast<const float2*>(xb + (size_t)(dd) * LL + 8)  \
                : make_float2(0.f, 0.f);

#define XCOMP(P0, P1, PH, dd)                                                   \
    {                                                                           \
        const float xs[10] = {P0.x, P0.y, P0.z, P0.w,                           \
                              P1.x, P1.y, P1.z, P1.w, PH.x, PH.y};              \
        const float* wr = wgt + (size_t)(dd) * 32;                              \
        _Pragma("unroll")                                                       \
        for (int o = 0; o < 10; ++o) {                                          \
            const float w0 = wr[o * 3];                                         \
            const float wA = wr[o * 3 + 1];                                     \
            const float wB = wr[o * 3 + 2];                                     \
            _Pragma("unroll")                                                   \
            for (int k = 0; k < 8; ++k)                                         \
                acc[o][k] = fmaf(xs[k + 2], wB,                                 \
                            fmaf(xs[k + 1], wA,                                 \
                            fmaf(xs[k],     w0, acc[o][k])));                   \
        }                                                                       \
    }

    float4 a0, a1; float2 ah;
    float4 c0, c1; float2 ch;
    XLOAD(a0, a1, ah, 0)
    #pragma unroll 1
    for (int d = 0; d < 30; d += 2) {
        XLOAD(c0, c1, ch, d + 1)
        XCOMP(a0, a1, ah, d)
        XLOAD(a0, a1, ah, d + 2)
        XCOMP(c0, c1, ch, d + 1)
    }
    XLOAD(c0, c1, ch, 31)
    XCOMP(a0, a1, ah, 30)
    XCOMP(c0, c1, ch, 31)
#undef XLOAD
#undef XCOMP

    #pragma unroll
    for (int o = 0; o < 10; ++o)
        #pragma unroll
        for (int k = 0; k < 8; ++k)
            acc[o][k] = fast_tanh(acc[o][k]);

    float* ob = out + (size_t)bg * OC_ * LP + l;
    const bool full = (l + 8 <= LP);
    #pragma unroll
    for (int dd = 0; dd < 10; ++dd) {
        const float* wr = weff + dd * 10;
        float r[8];
        const float bv = beff[dd];
        #pragma unroll
        for (int k = 0; k < 8; ++k) r[k] = bv;
        #pragma unroll
        for (int j = 0; j < 10; ++j) {
            const float w = wr[j];
            #pragma unroll
            for (int k = 0; k < 8; ++k) r[k] = fmaf(acc[j][k], w, r[k]);
        }
        float* op = ob + (size_t)dd * LP;
        if (full) {
            *reinterpret_cast<float2*>(op)     = make_float2(r[0], r[1]);
            *reinterpret_cast<float2*>(op + 2) = make_float2(r[2], r[3]);
            *reinterpret_cast<float2*>(op + 4) = make_float2(r[4], r[5]);
            *reinterpret_cast<float2*>(op + 6) = make_float2(r[6], r[7]);
        } else {
            #pragma unroll
            for (int k = 0; k < 8; ++k)
                if (l + k < LP) op[k] = r[k];
        }
    }
}

extern "C" void kernel_launch(void* const* d_in, const int* in_sizes, int n_in,
                              void* d_out, int out_size, void* d_ws, size_t ws_size,
                              hipStream_t stream) {
    (void)in_sizes; (void)n_in; (void)out_size; (void)ws_size;
    const float* x  = (const float*)d_in[0];
    const float* w1 = (const float*)d_in[1];
    const float* b1 = (const float*)d_in[2];
    const float* w2 = (const float*)d_in[3];
    const float* b2 = (const float*)d_in[4];
    const float* wg = (const float*)d_in[5];
    float* out      = (float*)d_out;
    float* gws      = (float*)d_ws;                         // [B,G,E]
    float* w1t      = (float*)d_ws + B_ * G_ * E_;          // [g][d][32]
    float* loss_out = out + COMBINE_SIZE;
    float* gout     = out + COMBINE_SIZE + 1;

    repack_kernel<<<(G_ * 32 * 30 + 255) / 256, 256, 0, stream>>>(w1, w1t);
    gate_kernel<<<B_, 64, 0, stream>>>(x, wg, gws, gout);
    loss_kernel<<<1, 64, 0, stream>>>(gws, loss_out);
    conv_kernel<<<B_ * G_ * 2, 256, 0, stream>>>(x, w1t, b1, w2, b2, gws, out);
}